// Round 6
// baseline (507.221 us; speedup 1.0000x reference)
//
#include <hip/hip_runtime.h>
#include <hip/hip_bf16.h>

// Texture_trans: patch-correlation texture transfer + residual conv stack.
// B=4, H=W=64, L=4096, C=64. ALL inputs/outputs fp32. Activations NHWC throughout.
// R18: (a) corr -> 4 waves x 64x64 frag tiles (R14/R16 verified structure; 1.5x
// less LDS read traffic/slot than R17's 8x32x64) + R17's VALU-light staging
// (per-lane base ptrs + uniform scalar offset) + setprio; inv0 computed in-kernel
// into LDS (norm_kernel deleted). (b) dispatches 13->9: wprep x5 -> 1; reduce
// fused into tgather (argmax from partials + inv1 + S written there).
// (c) convs byte-identical to R16/R17 (passed twice; two theories falsified).
// Workspace: 15,958,016 B, layout unchanged (inv0/inv1/arg slots now unused).

#define BATCH 4

typedef unsigned short u16;
typedef unsigned int   u32;
typedef __attribute__((ext_vector_type(8))) short short8;
typedef __attribute__((ext_vector_type(4))) float f32x4;

__device__ __forceinline__ void bsplit2(float a, float b, u32& ho, u32& lo) {
  __hip_bfloat16 ha = __float2bfloat16(a), hb = __float2bfloat16(b);
  float ra = a - __bfloat162float(ha), rb = b - __bfloat162float(hb);
  __hip_bfloat16 la = __float2bfloat16(ra), lb = __float2bfloat16(rb);
  ho = (u32)*(u16*)&ha | ((u32)*(u16*)&hb << 16);
  lo = (u32)*(u16*)&la | ((u32)*(u16*)&lb << 16);
}

__device__ __forceinline__ void gload_lds16(const void* g, void* l) {
  __builtin_amdgcn_global_load_lds((const __attribute__((address_space(1))) void*)g,
                                   (__attribute__((address_space(3))) void*)l, 16, 0, 0);
}

// ---------------- K3: split fp32 -> bf16 hi + lo into ZERO-PADDED [B][66][66][64]
// + fused per-pixel channel sum-of-squares (lanes = channels, 64-lane shfl reduce).
__global__ __launch_bounds__(256) void split_pad_kernel(const float* __restrict__ c0,
    const float* __restrict__ c1, u16* __restrict__ p0h, u16* __restrict__ p0l,
    u16* __restrict__ p1h, u16* __restrict__ p1l,
    float* __restrict__ ss0, float* __restrict__ ss1)
{
  int b = blockIdx.y, t = threadIdx.x;
  int pix = blockIdx.x * 4 + (t >> 6);   // 0..4355 over 66x66
  int c = t & 63;
  int py = pix / 66, px = pix - py * 66;
  size_t d = ((size_t)b * 4356 + pix) * 64 + c;
  bool interior = (py >= 1 && py <= 64 && px >= 1 && px <= 64);
  float v0 = 0.f, v1 = 0.f;
  if (interior) {
    size_t s = (((size_t)b << 12) + ((py - 1) << 6) + (px - 1)) * 64 + c;
    v0 = c0[s]; v1 = c1[s];
  }
  __hip_bfloat16 h = __float2bfloat16(v0);
  float r = v0 - __bfloat162float(h);
  __hip_bfloat16 lo = __float2bfloat16(r);
  p0h[d] = *(u16*)&h; p0l[d] = *(u16*)&lo;
  h = __float2bfloat16(v1);
  r = v1 - __bfloat162float(h);
  lo = __float2bfloat16(r);
  p1h[d] = *(u16*)&h; p1l[d] = *(u16*)&lo;
  float s0 = v0 * v0, s1 = v1 * v1;
#pragma unroll
  for (int off = 32; off; off >>= 1) {
    s0 += __shfl_xor(s0, off);
    s1 += __shfl_xor(s1, off);
  }
  if (c == 0 && interior) {
    int sstid = (b << 12) + ((py - 1) << 6) + (px - 1);
    ss0[sstid] = s0;
    ss1[sstid] = s1;
  }
}

// ---------------- K3b: ALL weight sets in one kernel. OIHW fp32 ->
// [tap][cout][cin] bf16 hi/lo. Block ranges hardcoded per set.
__global__ __launch_bounds__(256) void wprep_all(
    const float* __restrict__ hw, u16* __restrict__ whh, u16* __restrict__ whl,
    const float* __restrict__ r1, u16* __restrict__ w1h, u16* __restrict__ w1l,
    const float* __restrict__ r2, u16* __restrict__ w2h, u16* __restrict__ w2l,
    const float* __restrict__ tw, u16* __restrict__ wth, u16* __restrict__ wtl,
    const float* __restrict__ sw, u16* __restrict__ wsh, u16* __restrict__ wsl)
{
  int bid = blockIdx.x;
  const float* src; u16 *wh, *wl; int Cin, KK, n, i;
  if (bid < 400)       { src = hw; wh = whh; wl = whl; Cin = 64;  KK = 25; n = 102400; i = bid * 256; }
  else if (bid < 544)  { src = r1; wh = w1h; wl = w1l; Cin = 64;  KK = 9;  n = 36864;  i = (bid - 400) * 256; }
  else if (bid < 688)  { src = r2; wh = w2h; wl = w2l; Cin = 64;  KK = 9;  n = 36864;  i = (bid - 544) * 256; }
  else if (bid < 1088) { src = tw; wh = wth; wl = wtl; Cin = 64;  KK = 25; n = 102400; i = (bid - 688) * 256; }
  else                 { src = sw; wh = wsh; wl = wsl; Cin = 128; KK = 25; n = 204800; i = (bid - 1088) * 256; }
  i += threadIdx.x;
  if (i >= n) return;
  int per = Cin * KK;
  int cout = i / per;
  int rem = i - cout * per;
  int cin = rem / KK;
  int tap = rem - cin * KK;
  float x = src[i];
  __hip_bfloat16 h = __float2bfloat16(x);
  float r = x - __bfloat162float(h);
  __hip_bfloat16 lo = __float2bfloat16(r);
  int d = (tap * 64 + cout) * Cin + cin;
  wh[d] = *(u16*)&h;
  wl[d] = *(u16*)&lo;
}

// ---------------- K4: MFMA corr. 4 waves x 64x64 frag tiles (verified R14
// structure), double-buffered DMA pipeline, VALU-light staging, in-kernel inv0.
__global__ __launch_bounds__(256) void corr_mfma(const u16* __restrict__ p0h,
    const u16* __restrict__ p0l, const u16* __restrict__ p1h, const u16* __restrict__ p1l,
    const float* __restrict__ ss0, float* __restrict__ pval, int* __restrict__ pidx)
{
  __shared__ __align__(16) u16 smem[32768];   // 64 KB: 2 buf x (4 matrices x 4096)
  __shared__ float linv[512];                 // inv0 for this block's 512 rows
  int mt = blockIdx.x, lt = blockIdx.y, b = blockIdx.z;
  int t = threadIdx.x;
  int lane = t & 63, w = t >> 6;              // 4 waves
  int wl = w >> 1, wm = w & 1;
  int cc = lane & 15, q = lane >> 4;
  const size_t boff = (size_t)b * 278784;     // 66*66*64
  const u16* msrc = (w == 0) ? p0h : (w == 1) ? p0l : (w == 2) ? p1h : p1l;
  msrc += boff;
  int isB = w >> 1;

  int srow0 = lane >> 2;                      // row within 16-row chunk
  int cs_g  = (lane & 3) ^ ((lane >> 3) & 3); // source chunk for this lane's slot
  int sw    = (cc >> 1) & 3;                  // read-side swizzle key

  // inv0 for rows lt*512 .. +511 (replaces norm_kernel)
  {
    const float* ssb = ss0 + (b << 12);
    for (int r = t; r < 512; r += 256) {
      int l = (lt << 9) + r;
      int y = l >> 6, x = l & 63;
      float s = 0.f;
      for (int dy = -1; dy <= 1; ++dy) {
        int yy = y + dy; if ((unsigned)yy >= 64u) continue;
        for (int dx = -1; dx <= 1; ++dx) {
          int xx = x + dx; if ((unsigned)xx >= 64u) continue;
          s += ssb[(yy << 6) + xx];
        }
      }
      linv[r] = 1.f / fmaxf(sqrtf(s), 1e-12f);
    }
  }

  // per-lane base pointers for this wave's 8 staged chunks
  const u16* gb[8];
#pragma unroll
  for (int ii = 0; ii < 8; ++ii) {
    int k = (ii << 4) + srow0;                // pixel offset within 128-row tile
    gb[ii] = msrc + ((((k >> 6) * 66) + (k & 63)) << 6) + (cs_g << 3);
  }

  // stage: 8 DMA loads; address = gb[ii] + uniform scalar offset
  auto stage = [&](int ssub, int sph, u16* dst) {
    int r = sph >> 1, hh = sph & 1;
    int ki = r / 3, kj = r - ki * 3;
    int pbr = isB ? (mt << 1) : ((lt << 3) + (ssub << 1));   // rows/64
    int uoff = (((pbr + ki) * 66 + kj) << 6) + (hh << 5);    // wave-uniform
#pragma unroll
    for (int ii = 0; ii < 8; ++ii)
      gload_lds16(gb[ii] + uoff, dst + (ii << 9));
  };

  float bval[4] = {-1e30f, -1e30f, -1e30f, -1e30f};
  int   bidx[4] = {0, 0, 0, 0};

  stage(0, 0, smem + (w << 12));              // prologue into buffer 0

  for (int sub = 0; sub < 4; ++sub) {
    int row0 = (lt << 9) + (sub << 7);
    f32x4 acc[4][4];
#pragma unroll
    for (int i = 0; i < 4; ++i)
#pragma unroll
      for (int j = 0; j < 4; ++j) acc[i][j] = (f32x4){0.f, 0.f, 0.f, 0.f};

    for (int ph = 0; ph < 18; ++ph) {
      int g = sub * 18 + ph;
      int nxt = g + 1;
      if (nxt < 72) {
        int np = ph + 1, ns = sub;
        if (np == 18) { np = 0; ++ns; }
        stage(ns, np, smem + ((nxt & 1) << 14) + (w << 12));
        asm volatile("s_waitcnt vmcnt(8)" ::: "memory");   // phase g landed; g+1 in flight
      } else {
        asm volatile("s_waitcnt vmcnt(0)" ::: "memory");
      }
      __builtin_amdgcn_s_barrier();
      __builtin_amdgcn_sched_barrier(0);
      const u16* bb = smem + ((g & 1) << 14);
      short8 afh[4], afl[4], bfh[4], bfl[4];
#pragma unroll
      for (int i = 0; i < 4; ++i) {
        int ra = (((wl << 6) + (i << 4) + cc) << 5) + ((q ^ sw) << 3);
        afh[i] = *(const short8*)(&bb[ra]);
        afl[i] = *(const short8*)(&bb[4096 + ra]);
      }
#pragma unroll
      for (int j = 0; j < 4; ++j) {
        int rb = (((wm << 6) + (j << 4) + cc) << 5) + ((q ^ sw) << 3);
        bfh[j] = *(const short8*)(&bb[8192 + rb]);
        bfl[j] = *(const short8*)(&bb[12288 + rb]);
      }
      __builtin_amdgcn_s_setprio(1);
#pragma unroll
      for (int i = 0; i < 4; ++i)
#pragma unroll
        for (int j = 0; j < 4; ++j) {
          acc[i][j] = __builtin_amdgcn_mfma_f32_16x16x32_bf16(afh[i], bfl[j], acc[i][j], 0, 0, 0);
          acc[i][j] = __builtin_amdgcn_mfma_f32_16x16x32_bf16(afl[i], bfh[j], acc[i][j], 0, 0, 0);
          acc[i][j] = __builtin_amdgcn_mfma_f32_16x16x32_bf16(afh[i], bfh[j], acc[i][j], 0, 0, 0);
        }
      __builtin_amdgcn_s_setprio(0);
      __builtin_amdgcn_sched_barrier(0);
      __builtin_amdgcn_s_barrier();          // readers done before buf re-staged
    }
#pragma unroll
    for (int i = 0; i < 4; ++i) {
#pragma unroll
      for (int rg = 0; rg < 4; ++rg) {
        int r = (sub << 7) + (wl << 6) + (i << 4) + (q << 2) + rg;
        float sc = linv[r];
        int l = (lt << 9) + r;
#pragma unroll
        for (int j = 0; j < 4; ++j) {
          float v = acc[i][j][rg] * sc;
          if (v > bval[j]) { bval[j] = v; bidx[j] = l; }
        }
      }
    }
  }

  __syncthreads();                            // tiles dead; alias reduce buffers
  float* lval = (float*)smem;                 // 4096 B
  int*   lidx = (int*)((char*)smem + 4096);   // 4096 B
  int slot = (wl << 2) + q;
#pragma unroll
  for (int j = 0; j < 4; ++j) {
    int col = (wm << 6) + (j << 4) + cc;
    lval[col * 8 + slot] = bval[j];
    lidx[col * 8 + slot] = bidx[j];
  }
  __syncthreads();
  if (t < 128) {
    float bv = -1e30f; int bi = 0x7FFFFFFF;
    for (int s = 0; s < 8; ++s) {
      float v = lval[t * 8 + s]; int id = lidx[t * 8 + s];
      if (v > bv || (v == bv && id < bi)) { bv = v; bi = id; }
    }
    size_t o = (size_t)(((b << 3) + lt) << 12) + (mt << 7) + t;
    pval[o] = bv; pidx[o] = bi;
  }
}

// ---------------- K6: T = fold3(gather(f0_unfold, arg))/9 -> NHWC fp32.
// R18: fused reduce -- computes argmax from pval/pidx partials for its 3 rows,
// computes inv1 from ss1 box-sum and writes S for its own row.
__global__ __launch_bounds__(256) void tgather_kernel(const float* __restrict__ f0,
    const float* __restrict__ pval, const int* __restrict__ pidx,
    const float* __restrict__ ss1, float* __restrict__ S, float* __restrict__ T)
{
  __shared__ int a3[192];
  int y = blockIdx.x, b = blockIdx.y, t = threadIdx.x;
  if (t < 192) {
    int r = t >> 6, xx = t & 63;
    int yy = y + r - 1;
    bool ok = (yy >= 0 && yy < 64);
    float bv = -1e30f; int bi = 0x7FFFFFFF;
    if (ok) {
      int m = (yy << 6) + xx;
      for (int ltv = 0; ltv < 8; ++ltv) {
        size_t o = (size_t)(((b << 3) + ltv) << 12) + m;
        float v = pval[o]; int id = pidx[o];
        if (v > bv || (v == bv && id < bi)) { bv = v; bi = id; }
      }
      if (r == 1) {  // own row: compute inv1, write S
        const float* ssb = ss1 + (b << 12);
        float s = 0.f;
        for (int dy = -1; dy <= 1; ++dy) {
          int y2 = yy + dy; if ((unsigned)y2 >= 64u) continue;
          for (int dx = -1; dx <= 1; ++dx) {
            int x2 = xx + dx; if ((unsigned)x2 >= 64u) continue;
            s += ssb[(y2 << 6) + x2];
          }
        }
        S[(b << 12) + m] = bv / fmaxf(sqrtf(s), 1e-12f);
      }
    }
    a3[t] = (ok && (unsigned)bi < 4096u) ? bi : 0;
  }
  __syncthreads();
  int c = t & 63, pg = t >> 6;
  for (int it = 0; it < 16; ++it) {
    int px = pg + (it << 2);
    float sum = 0.f;
#pragma unroll
    for (int ki = 0; ki < 3; ++ki) {
      int yn = y + 1 - ki;
      if (yn < 0 || yn >= 64) continue;
#pragma unroll
      for (int kj = 0; kj < 3; ++kj) {
        int xn = px + 1 - kj;
        if (xn < 0 || xn >= 64) continue;
        int p = a3[((2 - ki) << 6) + xn];
        int sy = (p >> 6) + ki - 1, sx = (p & 63) + kj - 1;
        if (sy >= 0 && sy < 64 && sx >= 0 && sx < 64)
          sum += f0[((((size_t)b << 12) + (sy << 6) + sx) << 6) + c];
      }
    }
    T[((((size_t)b << 12) + (y << 6) + px)) * 64 + c] = sum * (1.f / 9.f);
  }
}

// ---------------- K7: implicit-GEMM MFMA conv (unchanged R16/R17).
template<int KS, int CINCH>
__global__ __launch_bounds__(256) void conv_mfma(const float* __restrict__ in0,
    const float* __restrict__ in1, const u16* __restrict__ whp, const u16* __restrict__ wlp,
    const float* __restrict__ bias, float* __restrict__ outp,
    const float* __restrict__ res, const float* __restrict__ smul, int dorelu, int dm)
{
  constexpr int P = KS / 2;
  constexpr int CIN = CINCH * 32;
  constexpr int NKH = CINCH / 2;              // # of 64-cin units
  constexpr int NIT = KS * KS * NKH;
  constexpr int AST = 72;                     // row stride in u16 (144 B, 16B-aligned)
  __shared__ __align__(16) u16 Ah[2][32 * AST], Al[2][32 * AST];
  __shared__ __align__(16) u16 Bh[2][64 * AST], Bl[2][64 * AST];
  int tile = blockIdx.x, b = blockIdx.y;      // y = tile>>1, px half = tile&1
  int t = threadIdx.x;
  int lane = t & 63, w = t >> 6;
  int wpx = w >> 1, wm = w & 1;
  int cc = lane & 15, q = lane >> 4;
  int ty = tile >> 1, txb = (tile & 1) << 5;
  const size_t abase = (size_t)b << 12;
  f32x4 acc[2];
  acc[0] = (f32x4){0.f, 0.f, 0.f, 0.f};
  acc[1] = (f32x4){0.f, 0.f, 0.f, 0.f};

  uint4 rg[8];                                // staging regs
  int arow = t >> 2, acs = t & 3;             // A mapping (t<128): 16-ch quarter
  int tb = t - 128;                           // B mapping (t>=128)
  int brow = tb >> 1, bhalf = tb & 1;         // 64 rows x 2 halves of 32 ch

  auto issue_loads = [&](int itn) {
    int tapn = (NKH == 1) ? itn : (itn >> 1);
    int kh   = (NKH == 1) ? 0 : (itn & 1);
    int ki = tapn / KS, kj = tapn - ki * KS;
    if (t < 128) {
#pragma unroll
      for (int k = 0; k < 8; ++k) rg[k] = make_uint4(0u, 0u, 0u, 0u);
      int iy = ty + ki - P;
      int ix = txb + arow + kj - P;
      if ((unsigned)iy < 64u && (unsigned)ix < 64u) {
        size_t base = (abase + (iy << 6) + ix) << 6;
        int cg = kh * 64 + acs * 16;
        if (dm) {
#pragma unroll
          for (int k = 0; k < 4; ++k) {
            rg[k]     = *(const uint4*)(in0 + base + cg + 4 * k);
            rg[4 + k] = *(const uint4*)(in1 + base + cg + 4 * k);
          }
        } else {
          const float* sp = (CINCH == 4 && kh == 1) ? (in1 + base + (cg - 64))
                                                    : (in0 + base + cg);
#pragma unroll
          for (int k = 0; k < 4; ++k) rg[k] = *(const uint4*)(sp + 4 * k);
        }
      }
    } else {
      size_t so = (size_t)(tapn * 64 + brow) * CIN + kh * 64 + bhalf * 32;
#pragma unroll
      for (int k = 0; k < 4; ++k) {
        rg[k]     = *(const uint4*)&whp[so + 8 * k];
        rg[4 + k] = *(const uint4*)&wlp[so + 8 * k];
      }
    }
  };

  auto write_lds = [&](int cur) {
    if (t < 128) {
      float v[16];
      if (dm) {
#pragma unroll
        for (int k = 0; k < 4; ++k)
#pragma unroll
          for (int e = 0; e < 4; ++e)
            v[k * 4 + e] = __uint_as_float((&rg[4 + k].x)[e]) - __uint_as_float((&rg[k].x)[e]);
      } else {
#pragma unroll
        for (int k = 0; k < 4; ++k)
#pragma unroll
          for (int e = 0; e < 4; ++e)
            v[k * 4 + e] = __uint_as_float((&rg[k].x)[e]);
      }
      uint4 uh0, ul0, uh1, ul1;
      bsplit2(v[0], v[1], uh0.x, ul0.x);
      bsplit2(v[2], v[3], uh0.y, ul0.y);
      bsplit2(v[4], v[5], uh0.z, ul0.z);
      bsplit2(v[6], v[7], uh0.w, ul0.w);
      bsplit2(v[8], v[9], uh1.x, ul1.x);
      bsplit2(v[10], v[11], uh1.y, ul1.y);
      bsplit2(v[12], v[13], uh1.z, ul1.z);
      bsplit2(v[14], v[15], uh1.w, ul1.w);
      int o = arow * AST + acs * 16;
      *(uint4*)&Ah[cur][o]     = uh0;
      *(uint4*)&Ah[cur][o + 8] = uh1;
      *(uint4*)&Al[cur][o]     = ul0;
      *(uint4*)&Al[cur][o + 8] = ul1;
    } else {
      int o = brow * AST + bhalf * 32;
#pragma unroll
      for (int k = 0; k < 4; ++k) {
        *(uint4*)&Bh[cur][o + 8 * k] = rg[k];
        *(uint4*)&Bl[cur][o + 8 * k] = rg[4 + k];
      }
    }
  };

  issue_loads(0);
  for (int it = 0; it < NIT; ++it) {
    int cur = it & 1;
    write_lds(cur);                            // consumes rg (vmcnt waits auto)
    if (it + 1 < NIT) issue_loads(it + 1);     // in flight across the barrier
    asm volatile("s_waitcnt lgkmcnt(0)" ::: "memory");
    __builtin_amdgcn_s_barrier();
    __builtin_amdgcn_sched_barrier(0);
    short8 afh[2], afl[2], bfh[2][2], bfl[2][2];
#pragma unroll
    for (int ks = 0; ks < 2; ++ks) {
      int ra = ((wpx << 4) + cc) * AST + ks * 32 + (q << 3);
      afh[ks] = *(const short8*)&Ah[cur][ra];
      afl[ks] = *(const short8*)&Al[cur][ra];
#pragma unroll
      for (int j = 0; j < 2; ++j) {
        int rb = ((wm << 5) + (j << 4) + cc) * AST + ks * 32 + (q << 3);
        bfh[j][ks] = *(const short8*)&Bh[cur][rb];
        bfl[j][ks] = *(const short8*)&Bl[cur][rb];
      }
    }
#pragma unroll
    for (int ks = 0; ks < 2; ++ks) {
      acc[0] = __builtin_amdgcn_mfma_f32_16x16x32_bf16(afh[ks], bfl[0][ks], acc[0], 0, 0, 0);
      acc[1] = __builtin_amdgcn_mfma_f32_16x16x32_bf16(afh[ks], bfl[1][ks], acc[1], 0, 0, 0);
      acc[0] = __builtin_amdgcn_mfma_f32_16x16x32_bf16(afl[ks], bfh[0][ks], acc[0], 0, 0, 0);
      acc[1] = __builtin_amdgcn_mfma_f32_16x16x32_bf16(afl[ks], bfh[1][ks], acc[1], 0, 0, 0);
      acc[0] = __builtin_amdgcn_mfma_f32_16x16x32_bf16(afh[ks], bfh[0][ks], acc[0], 0, 0, 0);
      acc[1] = __builtin_amdgcn_mfma_f32_16x16x32_bf16(afh[ks], bfh[1][ks], acc[1], 0, 0, 0);
    }
  }
#pragma unroll
  for (int rgi = 0; rgi < 4; ++rgi) {
    int p = (ty << 6) + txb + (wpx << 4) + (q << 2) + rgi;
#pragma unroll
    for (int j = 0; j < 2; ++j) {
      int cout = (wm << 5) + (j << 4) + cc;
      float v = acc[j][rgi] + bias[cout];
      if (dorelu) v = fmaxf(v, 0.f);
      size_t oi = ((abase + p) << 6) + cout;
      if (smul) v = res[oi] + v * smul[abase + p];
      else if (res) v += res[oi];
      outp[oi] = v;
    }
  }
}

extern "C" void kernel_launch(void* const* d_in, const int* in_sizes, int n_in,
                              void* d_out, int out_size, void* d_ws, size_t ws_size,
                              hipStream_t stream)
{
  (void)in_sizes; (void)n_in; (void)out_size; (void)ws_size;
  const float* c0     = (const float*)d_in[0];
  const float* f0     = (const float*)d_in[1];
  const float* c1     = (const float*)d_in[2];
  const float* head_w = (const float*)d_in[3];
  const float* head_b = (const float*)d_in[4];
  const float* rb_w1  = (const float*)d_in[5];
  const float* rb_b1  = (const float*)d_in[6];
  const float* rb_w2  = (const float*)d_in[7];
  const float* rb_b2  = (const float*)d_in[8];
  const float* tail_w = (const float*)d_in[9];
  const float* tail_b = (const float*)d_in[10];
  const float* sq_w   = (const float*)d_in[11];
  const float* sq_b   = (const float*)d_in[12];
  float* out = (float*)d_out;
  char* ws = (char*)d_ws;

  // ---- layout: 15,958,016 B total (unchanged; INV0/INV1/ARG slots unused) ----
  const size_t OFF_SS0  = 0;
  const size_t OFF_SS1  = 65536;
  const size_t OFF_S    = 262144;
  const size_t OFF_PVAL = 393216;       // 512 KB
  const size_t OFF_PIDX = 917504;       // 512 KB
  const size_t OFF_WHH  = 1441792;      // head  hi 204800
  const size_t OFF_WHL  = 1646592;      // head  lo 204800
  const size_t OFF_W1H  = 1851392;      // rb1   hi 73728
  const size_t OFF_W1L  = 1925120;
  const size_t OFF_W2H  = 1998848;      // rb2   hi 73728
  const size_t OFF_W2L  = 2072576;
  const size_t OFF_WTH  = 2146304;      // tail  hi 204800
  const size_t OFF_WTL  = 2351104;
  const size_t OFF_WSH  = 2555904;      // sq    hi 409600
  const size_t OFF_WSL  = 2965504;
  const size_t OFF_P0H  = 3375104;
  const size_t OFF_P0L  = OFF_P0H + 2230272;   // 5,605,376
  const size_t OFF_P1H  = OFF_P0L + 2230272;   // 7,835,648
  const size_t OFF_P1L  = OFF_P1H + 2230272;   // 10,065,920 (end 12,296,192)
  const size_t OFF_SA   = 3375104;      // 4 MB: x1 -> T
  const size_t OFF_SB   = 7569408;      // 4 MB: hb -> dcf
  const size_t OFF_SC   = 11763712;     // 4 MB: xb

  float* ss0  = (float*)(ws + OFF_SS0);
  float* ss1  = (float*)(ws + OFF_SS1);
  float* Sbuf = (float*)(ws + OFF_S);
  float* pval = (float*)(ws + OFF_PVAL);
  int*   pidx = (int*)(ws + OFF_PIDX);
  u16* whh = (u16*)(ws + OFF_WHH); u16* whl = (u16*)(ws + OFF_WHL);
  u16* w1h = (u16*)(ws + OFF_W1H); u16* w1l = (u16*)(ws + OFF_W1L);
  u16* w2h = (u16*)(ws + OFF_W2H); u16* w2l = (u16*)(ws + OFF_W2L);
  u16* wth = (u16*)(ws + OFF_WTH); u16* wtl = (u16*)(ws + OFF_WTL);
  u16* wsh = (u16*)(ws + OFF_WSH); u16* wsl = (u16*)(ws + OFF_WSL);
  u16* p0h = (u16*)(ws + OFF_P0H); u16* p0l = (u16*)(ws + OFF_P0L);
  u16* p1h = (u16*)(ws + OFF_P1H); u16* p1l = (u16*)(ws + OFF_P1L);
  float* x1  = (float*)(ws + OFF_SA);
  float* Tb  = (float*)(ws + OFF_SA);
  float* hb  = (float*)(ws + OFF_SB);
  float* dcf = (float*)(ws + OFF_SB);
  float* xb  = (float*)(ws + OFF_SC);

  dim3 b256(256);
  split_pad_kernel<<<dim3(1089, BATCH), b256, 0, stream>>>(c0, c1, p0h, p0l, p1h, p1l, ss0, ss1);
  wprep_all<<<dim3(1888), b256, 0, stream>>>(head_w, whh, whl,
      rb_w1 + 110592, w1h, w1l, rb_w2 + 110592, w2h, w2l,
      tail_w, wth, wtl, sq_w, wsh, wsl);

  corr_mfma<<<dim3(32, 8, BATCH), b256, 0, stream>>>(p0h, p0l, p1h, p1l, ss0, pval, pidx);

  // conv stack (only residual block 3 affects output); all NHWC.
  // Stream-ordered: these overwrite the padded-split region, which is dead now.
  dim3 cgrid(128, BATCH);
  conv_mfma<5, 2><<<cgrid, b256, 0, stream>>>(c0, c1, whh, whl, head_b, x1, nullptr, nullptr, 0, 1);
  conv_mfma<3, 2><<<cgrid, b256, 0, stream>>>(x1, nullptr, w1h, w1l, rb_b1 + 192, hb, nullptr, nullptr, 1, 0);
  conv_mfma<3, 2><<<cgrid, b256, 0, stream>>>(hb, nullptr, w2h, w2l, rb_b2 + 192, xb, x1, nullptr, 0, 0);
  conv_mfma<5, 2><<<cgrid, b256, 0, stream>>>(xb, nullptr, wth, wtl, tail_b, dcf, x1, nullptr, 0, 0);

  // tgather (+fused reduce: argmax, inv1, S). x1 dead after conv4; Tb aliases it.
  tgather_kernel<<<dim3(64, BATCH), b256, 0, stream>>>(f0, pval, pidx, ss1, Sbuf, Tb);
  // conv5 with fused final: out = dcf + conv*S, written directly to output (NLC==NHWC)
  conv_mfma<5, 4><<<cgrid, b256, 0, stream>>>(dcf, Tb, wsh, wsl, sq_b, out, dcf, Sbuf, 0, 0);
}

// Round 7
// 505.167 us; speedup vs baseline: 1.0041x; 1.0041x over previous
//
#include <hip/hip_runtime.h>
#include <hip/hip_bf16.h>

// Texture_trans: patch-correlation texture transfer + residual conv stack.
// B=4, H=W=64, L=4096, C=64. ALL inputs/outputs fp32. Activations NHWC throughout.
// R19 = best-of(R17, R18): corr byte-identical to R17's 8-wave kernel (211 us
// measured: 512 thr, 2x4 frags/wave, vmcnt(4), per-lane base ptrs, setprio);
// inv0 produced by 64 extra blocks appended to wprep_all (no extra dispatch,
// stream-ordered after split_pad). Non-corr half byte-identical to R18 (253 us
// measured: 9->8 dispatches, fused reduce/inv1/S into tgather, fused final into
// conv5). Workspace: 15,958,016 B, layout unchanged.

#define BATCH 4

typedef unsigned short u16;
typedef unsigned int   u32;
typedef __attribute__((ext_vector_type(8))) short short8;
typedef __attribute__((ext_vector_type(4))) float f32x4;

__device__ __forceinline__ void bsplit2(float a, float b, u32& ho, u32& lo) {
  __hip_bfloat16 ha = __float2bfloat16(a), hb = __float2bfloat16(b);
  float ra = a - __bfloat162float(ha), rb = b - __bfloat162float(hb);
  __hip_bfloat16 la = __float2bfloat16(ra), lb = __float2bfloat16(rb);
  ho = (u32)*(u16*)&ha | ((u32)*(u16*)&hb << 16);
  lo = (u32)*(u16*)&la | ((u32)*(u16*)&lb << 16);
}

__device__ __forceinline__ void gload_lds16(const void* g, void* l) {
  __builtin_amdgcn_global_load_lds((const __attribute__((address_space(1))) void*)g,
                                   (__attribute__((address_space(3))) void*)l, 16, 0, 0);
}

// ---------------- K3: split fp32 -> bf16 hi + lo into ZERO-PADDED [B][66][66][64]
// + fused per-pixel channel sum-of-squares (lanes = channels, 64-lane shfl reduce).
__global__ __launch_bounds__(256) void split_pad_kernel(const float* __restrict__ c0,
    const float* __restrict__ c1, u16* __restrict__ p0h, u16* __restrict__ p0l,
    u16* __restrict__ p1h, u16* __restrict__ p1l,
    float* __restrict__ ss0, float* __restrict__ ss1)
{
  int b = blockIdx.y, t = threadIdx.x;
  int pix = blockIdx.x * 4 + (t >> 6);   // 0..4355 over 66x66
  int c = t & 63;
  int py = pix / 66, px = pix - py * 66;
  size_t d = ((size_t)b * 4356 + pix) * 64 + c;
  bool interior = (py >= 1 && py <= 64 && px >= 1 && px <= 64);
  float v0 = 0.f, v1 = 0.f;
  if (interior) {
    size_t s = (((size_t)b << 12) + ((py - 1) << 6) + (px - 1)) * 64 + c;
    v0 = c0[s]; v1 = c1[s];
  }
  __hip_bfloat16 h = __float2bfloat16(v0);
  float r = v0 - __bfloat162float(h);
  __hip_bfloat16 lo = __float2bfloat16(r);
  p0h[d] = *(u16*)&h; p0l[d] = *(u16*)&lo;
  h = __float2bfloat16(v1);
  r = v1 - __bfloat162float(h);
  lo = __float2bfloat16(r);
  p1h[d] = *(u16*)&h; p1l[d] = *(u16*)&lo;
  float s0 = v0 * v0, s1 = v1 * v1;
#pragma unroll
  for (int off = 32; off; off >>= 1) {
    s0 += __shfl_xor(s0, off);
    s1 += __shfl_xor(s1, off);
  }
  if (c == 0 && interior) {
    int sstid = (b << 12) + ((py - 1) << 6) + (px - 1);
    ss0[sstid] = s0;
    ss1[sstid] = s1;
  }
}

// ---------------- K3b: ALL weight sets + inv0 in one kernel.
// Blocks 0..1887: OIHW fp32 -> [tap][cout][cin] bf16 hi/lo.
// Blocks 1888..1951: inv0 = 1/max(sqrt(box3(ss0)), EPS)  (stream-ordered after split_pad).
__global__ __launch_bounds__(256) void wprep_all(
    const float* __restrict__ hw, u16* __restrict__ whh, u16* __restrict__ whl,
    const float* __restrict__ r1, u16* __restrict__ w1h, u16* __restrict__ w1l,
    const float* __restrict__ r2, u16* __restrict__ w2h, u16* __restrict__ w2l,
    const float* __restrict__ tw, u16* __restrict__ wth, u16* __restrict__ wtl,
    const float* __restrict__ sw, u16* __restrict__ wsh, u16* __restrict__ wsl,
    const float* __restrict__ ss0, float* __restrict__ inv0)
{
  int bid = blockIdx.x;
  if (bid >= 1888) {                     // inv0 tail: 64 blocks cover 4x4096
    int tid = (bid - 1888) * 256 + threadIdx.x;
    int b = tid >> 12, l = tid & 4095;
    int y = l >> 6, x = l & 63;
    const float* ssb = ss0 + (b << 12);
    float s = 0.f;
    for (int dy = -1; dy <= 1; ++dy) {
      int yy = y + dy; if ((unsigned)yy >= 64u) continue;
      for (int dx = -1; dx <= 1; ++dx) {
        int xx = x + dx; if ((unsigned)xx >= 64u) continue;
        s += ssb[(yy << 6) + xx];
      }
    }
    inv0[tid] = 1.f / fmaxf(sqrtf(s), 1e-12f);
    return;
  }
  const float* src; u16 *wh, *wl; int Cin, KK, n, i;
  if (bid < 400)       { src = hw; wh = whh; wl = whl; Cin = 64;  KK = 25; n = 102400; i = bid * 256; }
  else if (bid < 544)  { src = r1; wh = w1h; wl = w1l; Cin = 64;  KK = 9;  n = 36864;  i = (bid - 400) * 256; }
  else if (bid < 688)  { src = r2; wh = w2h; wl = w2l; Cin = 64;  KK = 9;  n = 36864;  i = (bid - 544) * 256; }
  else if (bid < 1088) { src = tw; wh = wth; wl = wtl; Cin = 64;  KK = 25; n = 102400; i = (bid - 688) * 256; }
  else                 { src = sw; wh = wsh; wl = wsl; Cin = 128; KK = 25; n = 204800; i = (bid - 1088) * 256; }
  i += threadIdx.x;
  if (i >= n) return;
  int per = Cin * KK;
  int cout = i / per;
  int rem = i - cout * per;
  int cin = rem / KK;
  int tap = rem - cin * KK;
  float x = src[i];
  __hip_bfloat16 h = __float2bfloat16(x);
  float r = x - __bfloat162float(h);
  __hip_bfloat16 lo = __float2bfloat16(r);
  int d = (tap * 64 + cout) * Cin + cin;
  wh[d] = *(u16*)&h;
  wl[d] = *(u16*)&lo;
}

// ---------------- K4: MFMA corr. Byte-identical to R17 (measured 211 us).
// 8 waves: staging matrix = w>>1, half = w&1 (4 gload_lds/phase). Compute:
// A-quarter wa = w>>1 (32 rows, 2 frags), B-half wm = w&1 (64 cols, 4 frags).
__global__ __launch_bounds__(512) void corr_mfma(const u16* __restrict__ p0h,
    const u16* __restrict__ p0l, const u16* __restrict__ p1h, const u16* __restrict__ p1l,
    const float* __restrict__ inv0, float* __restrict__ pval, int* __restrict__ pidx)
{
  __shared__ __align__(16) u16 smem[32768];   // 64 KB: 2 buf x (4 matrices x 4096)
  int mt = blockIdx.x, lt = blockIdx.y, b = blockIdx.z;
  int t = threadIdx.x;
  int lane = t & 63, w = t >> 6;              // w in 0..7
  int wa = w >> 1, wm = w & 1;                // A-quarter / B-half (compute)
  int mat = w >> 1, half = w & 1;             // staging matrix / half
  int cc = lane & 15, q = lane >> 4;
  const size_t boff = (size_t)b * 278784;     // 66*66*64
  const u16* msrc = (mat == 0) ? p0h : (mat == 1) ? p0l : (mat == 2) ? p1h : p1l;
  msrc += boff;
  const float* inv0b = inv0 + (b << 12);
  int isB = mat >> 1;

  int srow0 = lane >> 2;                      // row within 16-row chunk
  int cs_g  = (lane & 3) ^ ((lane >> 3) & 3); // source chunk for this lane's slot
  int sw    = (cc >> 1) & 3;                  // read-side swizzle key

  const u16* gb[4];
#pragma unroll
  for (int ii = 0; ii < 4; ++ii) {
    int k = ((half * 4 + ii) << 4) + srow0;   // pixel offset within 128-row tile
    gb[ii] = msrc + ((((k >> 6) * 66) + (k & 63)) << 6) + (cs_g << 3);
  }

  auto stage = [&](int ssub, int sph, u16* dstbase) {
    int r = sph >> 1, hh = sph & 1;
    int ki = r / 3, kj = r - ki * 3;
    int pbr = isB ? (mt << 1) : ((lt << 3) + (ssub << 1));   // pb>>6 (rows)
    int uoff = (((pbr + ki) * 66 + kj) << 6) + (hh << 5);    // wave-uniform
#pragma unroll
    for (int ii = 0; ii < 4; ++ii)
      gload_lds16(gb[ii] + uoff, dstbase + ((half * 4 + ii) << 9));
  };

  float bval[4] = {-1e30f, -1e30f, -1e30f, -1e30f};
  int   bidx[4] = {0, 0, 0, 0};

  stage(0, 0, smem + (mat << 12));            // prologue into buffer 0

  for (int sub = 0; sub < 4; ++sub) {
    int row0 = (lt << 9) + (sub << 7);
    f32x4 acc[2][4];
#pragma unroll
    for (int i = 0; i < 2; ++i)
#pragma unroll
      for (int j = 0; j < 4; ++j) acc[i][j] = (f32x4){0.f, 0.f, 0.f, 0.f};

    for (int ph = 0; ph < 18; ++ph) {
      int g = sub * 18 + ph;
      int nxt = g + 1;
      if (nxt < 72) {
        int np = ph + 1, ns = sub;
        if (np == 18) { np = 0; ++ns; }
        stage(ns, np, smem + ((nxt & 1) << 14) + (mat << 12));
        asm volatile("s_waitcnt vmcnt(4)" ::: "memory");   // phase g landed; g+1 in flight
      } else {
        asm volatile("s_waitcnt vmcnt(0)" ::: "memory");
      }
      __builtin_amdgcn_s_barrier();
      __builtin_amdgcn_sched_barrier(0);
      const u16* bb = smem + ((g & 1) << 14);
      short8 afh[2], afl[2], bfh[4], bfl[4];
#pragma unroll
      for (int i = 0; i < 2; ++i) {
        int ra = (((wa << 5) + (i << 4) + cc) << 5) + ((q ^ sw) << 3);
        afh[i] = *(const short8*)(&bb[ra]);
        afl[i] = *(const short8*)(&bb[4096 + ra]);
      }
#pragma unroll
      for (int j = 0; j < 4; ++j) {
        int rb = (((wm << 6) + (j << 4) + cc) << 5) + ((q ^ sw) << 3);
        bfh[j] = *(const short8*)(&bb[8192 + rb]);
        bfl[j] = *(const short8*)(&bb[12288 + rb]);
      }
      __builtin_amdgcn_s_setprio(1);
#pragma unroll
      for (int i = 0; i < 2; ++i)
#pragma unroll
        for (int j = 0; j < 4; ++j) {
          acc[i][j] = __builtin_amdgcn_mfma_f32_16x16x32_bf16(afh[i], bfl[j], acc[i][j], 0, 0, 0);
          acc[i][j] = __builtin_amdgcn_mfma_f32_16x16x32_bf16(afl[i], bfh[j], acc[i][j], 0, 0, 0);
          acc[i][j] = __builtin_amdgcn_mfma_f32_16x16x32_bf16(afh[i], bfh[j], acc[i][j], 0, 0, 0);
        }
      __builtin_amdgcn_s_setprio(0);
      __builtin_amdgcn_sched_barrier(0);
      __builtin_amdgcn_s_barrier();          // readers done before buf re-staged
    }
#pragma unroll
    for (int i = 0; i < 2; ++i) {
#pragma unroll
      for (int rg = 0; rg < 4; ++rg) {
        int l = row0 + (wa << 5) + (i << 4) + (q << 2) + rg;
        float sc = inv0b[l];
#pragma unroll
        for (int j = 0; j < 4; ++j) {
          float v = acc[i][j][rg] * sc;
          if (v > bval[j]) { bval[j] = v; bidx[j] = l; }
        }
      }
    }
  }

  __syncthreads();                            // tiles dead; alias reduce buffers
  float* lval = (float*)smem;                 // 128 cols x 16 slots = 8 KB
  int*   lidx = (int*)((char*)smem + 8192);   // 8 KB
  int slot = (wa << 2) + q;
#pragma unroll
  for (int j = 0; j < 4; ++j) {
    int col = (wm << 6) + (j << 4) + cc;
    lval[col * 16 + slot] = bval[j];
    lidx[col * 16 + slot] = bidx[j];
  }
  __syncthreads();
  if (t < 128) {
    float bv = -1e30f; int bi = 0x7FFFFFFF;
    for (int s = 0; s < 16; ++s) {
      float v = lval[t * 16 + s]; int id = lidx[t * 16 + s];
      if (v > bv || (v == bv && id < bi)) { bv = v; bi = id; }
    }
    size_t o = (size_t)(((b << 3) + lt) << 12) + (mt << 7) + t;
    pval[o] = bv; pidx[o] = bi;
  }
}

// ---------------- K6: T = fold3(gather(f0_unfold, arg))/9 -> NHWC fp32.
// Fused reduce: argmax from pval/pidx for its 3 rows; inv1 + S for its own row.
__global__ __launch_bounds__(256) void tgather_kernel(const float* __restrict__ f0,
    const float* __restrict__ pval, const int* __restrict__ pidx,
    const float* __restrict__ ss1, float* __restrict__ S, float* __restrict__ T)
{
  __shared__ int a3[192];
  int y = blockIdx.x, b = blockIdx.y, t = threadIdx.x;
  if (t < 192) {
    int r = t >> 6, xx = t & 63;
    int yy = y + r - 1;
    bool ok = (yy >= 0 && yy < 64);
    float bv = -1e30f; int bi = 0x7FFFFFFF;
    if (ok) {
      int m = (yy << 6) + xx;
      for (int ltv = 0; ltv < 8; ++ltv) {
        size_t o = (size_t)(((b << 3) + ltv) << 12) + m;
        float v = pval[o]; int id = pidx[o];
        if (v > bv || (v == bv && id < bi)) { bv = v; bi = id; }
      }
      if (r == 1) {  // own row: compute inv1, write S
        const float* ssb = ss1 + (b << 12);
        float s = 0.f;
        for (int dy = -1; dy <= 1; ++dy) {
          int y2 = yy + dy; if ((unsigned)y2 >= 64u) continue;
          for (int dx = -1; dx <= 1; ++dx) {
            int x2 = xx + dx; if ((unsigned)x2 >= 64u) continue;
            s += ssb[(y2 << 6) + x2];
          }
        }
        S[(b << 12) + m] = bv / fmaxf(sqrtf(s), 1e-12f);
      }
    }
    a3[t] = (ok && (unsigned)bi < 4096u) ? bi : 0;
  }
  __syncthreads();
  int c = t & 63, pg = t >> 6;
  for (int it = 0; it < 16; ++it) {
    int px = pg + (it << 2);
    float sum = 0.f;
#pragma unroll
    for (int ki = 0; ki < 3; ++ki) {
      int yn = y + 1 - ki;
      if (yn < 0 || yn >= 64) continue;
#pragma unroll
      for (int kj = 0; kj < 3; ++kj) {
        int xn = px + 1 - kj;
        if (xn < 0 || xn >= 64) continue;
        int p = a3[((2 - ki) << 6) + xn];
        int sy = (p >> 6) + ki - 1, sx = (p & 63) + kj - 1;
        if (sy >= 0 && sy < 64 && sx >= 0 && sx < 64)
          sum += f0[((((size_t)b << 12) + (sy << 6) + sx) << 6) + c];
      }
    }
    T[((((size_t)b << 12) + (y << 6) + px)) * 64 + c] = sum * (1.f / 9.f);
  }
}

// ---------------- K7: implicit-GEMM MFMA conv (unchanged R16/R17/R18).
template<int KS, int CINCH>
__global__ __launch_bounds__(256) void conv_mfma(const float* __restrict__ in0,
    const float* __restrict__ in1, const u16* __restrict__ whp, const u16* __restrict__ wlp,
    const float* __restrict__ bias, float* __restrict__ outp,
    const float* __restrict__ res, const float* __restrict__ smul, int dorelu, int dm)
{
  constexpr int P = KS / 2;
  constexpr int CIN = CINCH * 32;
  constexpr int NKH = CINCH / 2;              // # of 64-cin units
  constexpr int NIT = KS * KS * NKH;
  constexpr int AST = 72;                     // row stride in u16 (144 B, 16B-aligned)
  __shared__ __align__(16) u16 Ah[2][32 * AST], Al[2][32 * AST];
  __shared__ __align__(16) u16 Bh[2][64 * AST], Bl[2][64 * AST];
  int tile = blockIdx.x, b = blockIdx.y;      // y = tile>>1, px half = tile&1
  int t = threadIdx.x;
  int lane = t & 63, w = t >> 6;
  int wpx = w >> 1, wm = w & 1;
  int cc = lane & 15, q = lane >> 4;
  int ty = tile >> 1, txb = (tile & 1) << 5;
  const size_t abase = (size_t)b << 12;
  f32x4 acc[2];
  acc[0] = (f32x4){0.f, 0.f, 0.f, 0.f};
  acc[1] = (f32x4){0.f, 0.f, 0.f, 0.f};

  uint4 rg[8];                                // staging regs
  int arow = t >> 2, acs = t & 3;             // A mapping (t<128): 16-ch quarter
  int tb = t - 128;                           // B mapping (t>=128)
  int brow = tb >> 1, bhalf = tb & 1;         // 64 rows x 2 halves of 32 ch

  auto issue_loads = [&](int itn) {
    int tapn = (NKH == 1) ? itn : (itn >> 1);
    int kh   = (NKH == 1) ? 0 : (itn & 1);
    int ki = tapn / KS, kj = tapn - ki * KS;
    if (t < 128) {
#pragma unroll
      for (int k = 0; k < 8; ++k) rg[k] = make_uint4(0u, 0u, 0u, 0u);
      int iy = ty + ki - P;
      int ix = txb + arow + kj - P;
      if ((unsigned)iy < 64u && (unsigned)ix < 64u) {
        size_t base = (abase + (iy << 6) + ix) << 6;
        int cg = kh * 64 + acs * 16;
        if (dm) {
#pragma unroll
          for (int k = 0; k < 4; ++k) {
            rg[k]     = *(const uint4*)(in0 + base + cg + 4 * k);
            rg[4 + k] = *(const uint4*)(in1 + base + cg + 4 * k);
          }
        } else {
          const float* sp = (CINCH == 4 && kh == 1) ? (in1 + base + (cg - 64))
                                                    : (in0 + base + cg);
#pragma unroll
          for (int k = 0; k < 4; ++k) rg[k] = *(const uint4*)(sp + 4 * k);
        }
      }
    } else {
      size_t so = (size_t)(tapn * 64 + brow) * CIN + kh * 64 + bhalf * 32;
#pragma unroll
      for (int k = 0; k < 4; ++k) {
        rg[k]     = *(const uint4*)&whp[so + 8 * k];
        rg[4 + k] = *(const uint4*)&wlp[so + 8 * k];
      }
    }
  };

  auto write_lds = [&](int cur) {
    if (t < 128) {
      float v[16];
      if (dm) {
#pragma unroll
        for (int k = 0; k < 4; ++k)
#pragma unroll
          for (int e = 0; e < 4; ++e)
            v[k * 4 + e] = __uint_as_float((&rg[4 + k].x)[e]) - __uint_as_float((&rg[k].x)[e]);
      } else {
#pragma unroll
        for (int k = 0; k < 4; ++k)
#pragma unroll
          for (int e = 0; e < 4; ++e)
            v[k * 4 + e] = __uint_as_float((&rg[k].x)[e]);
      }
      uint4 uh0, ul0, uh1, ul1;
      bsplit2(v[0], v[1], uh0.x, ul0.x);
      bsplit2(v[2], v[3], uh0.y, ul0.y);
      bsplit2(v[4], v[5], uh0.z, ul0.z);
      bsplit2(v[6], v[7], uh0.w, ul0.w);
      bsplit2(v[8], v[9], uh1.x, ul1.x);
      bsplit2(v[10], v[11], uh1.y, ul1.y);
      bsplit2(v[12], v[13], uh1.z, ul1.z);
      bsplit2(v[14], v[15], uh1.w, ul1.w);
      int o = arow * AST + acs * 16;
      *(uint4*)&Ah[cur][o]     = uh0;
      *(uint4*)&Ah[cur][o + 8] = uh1;
      *(uint4*)&Al[cur][o]     = ul0;
      *(uint4*)&Al[cur][o + 8] = ul1;
    } else {
      int o = brow * AST + bhalf * 32;
#pragma unroll
      for (int k = 0; k < 4; ++k) {
        *(uint4*)&Bh[cur][o + 8 * k] = rg[k];
        *(uint4*)&Bl[cur][o + 8 * k] = rg[4 + k];
      }
    }
  };

  issue_loads(0);
  for (int it = 0; it < NIT; ++it) {
    int cur = it & 1;
    write_lds(cur);                            // consumes rg (vmcnt waits auto)
    if (it + 1 < NIT) issue_loads(it + 1);     // in flight across the barrier
    asm volatile("s_waitcnt lgkmcnt(0)" ::: "memory");
    __builtin_amdgcn_s_barrier();
    __builtin_amdgcn_sched_barrier(0);
    short8 afh[2], afl[2], bfh[2][2], bfl[2][2];
#pragma unroll
    for (int ks = 0; ks < 2; ++ks) {
      int ra = ((wpx << 4) + cc) * AST + ks * 32 + (q << 3);
      afh[ks] = *(const short8*)&Ah[cur][ra];
      afl[ks] = *(const short8*)&Al[cur][ra];
#pragma unroll
      for (int j = 0; j < 2; ++j) {
        int rb = ((wm << 5) + (j << 4) + cc) * AST + ks * 32 + (q << 3);
        bfh[j][ks] = *(const short8*)&Bh[cur][rb];
        bfl[j][ks] = *(const short8*)&Bl[cur][rb];
      }
    }
#pragma unroll
    for (int ks = 0; ks < 2; ++ks) {
      acc[0] = __builtin_amdgcn_mfma_f32_16x16x32_bf16(afh[ks], bfl[0][ks], acc[0], 0, 0, 0);
      acc[1] = __builtin_amdgcn_mfma_f32_16x16x32_bf16(afh[ks], bfl[1][ks], acc[1], 0, 0, 0);
      acc[0] = __builtin_amdgcn_mfma_f32_16x16x32_bf16(afl[ks], bfh[0][ks], acc[0], 0, 0, 0);
      acc[1] = __builtin_amdgcn_mfma_f32_16x16x32_bf16(afl[ks], bfh[1][ks], acc[1], 0, 0, 0);
      acc[0] = __builtin_amdgcn_mfma_f32_16x16x32_bf16(afh[ks], bfh[0][ks], acc[0], 0, 0, 0);
      acc[1] = __builtin_amdgcn_mfma_f32_16x16x32_bf16(afh[ks], bfh[1][ks], acc[1], 0, 0, 0);
    }
  }
#pragma unroll
  for (int rgi = 0; rgi < 4; ++rgi) {
    int p = (ty << 6) + txb + (wpx << 4) + (q << 2) + rgi;
#pragma unroll
    for (int j = 0; j < 2; ++j) {
      int cout = (wm << 5) + (j << 4) + cc;
      float v = acc[j][rgi] + bias[cout];
      if (dorelu) v = fmaxf(v, 0.f);
      size_t oi = ((abase + p) << 6) + cout;
      if (smul) v = res[oi] + v * smul[abase + p];
      else if (res) v += res[oi];
      outp[oi] = v;
    }
  }
}

extern "C" void kernel_launch(void* const* d_in, const int* in_sizes, int n_in,
                              void* d_out, int out_size, void* d_ws, size_t ws_size,
                              hipStream_t stream)
{
  (void)in_sizes; (void)n_in; (void)out_size; (void)ws_size;
  const float* c0     = (const float*)d_in[0];
  const float* f0     = (const float*)d_in[1];
  const float* c1     = (const float*)d_in[2];
  const float* head_w = (const float*)d_in[3];
  const float* head_b = (const float*)d_in[4];
  const float* rb_w1  = (const float*)d_in[5];
  const float* rb_b1  = (const float*)d_in[6];
  const float* rb_w2  = (const float*)d_in[7];
  const float* rb_b2  = (const float*)d_in[8];
  const float* tail_w = (const float*)d_in[9];
  const float* tail_b = (const float*)d_in[10];
  const float* sq_w   = (const float*)d_in[11];
  const float* sq_b   = (const float*)d_in[12];
  float* out = (float*)d_out;
  char* ws = (char*)d_ws;

  // ---- layout: 15,958,016 B total (unchanged) ----
  const size_t OFF_SS0  = 0;
  const size_t OFF_SS1  = 65536;
  const size_t OFF_INV0 = 131072;
  const size_t OFF_S    = 262144;
  const size_t OFF_PVAL = 393216;       // 512 KB
  const size_t OFF_PIDX = 917504;       // 512 KB
  const size_t OFF_WHH  = 1441792;      // head  hi 204800
  const size_t OFF_WHL  = 1646592;      // head  lo 204800
  const size_t OFF_W1H  = 1851392;      // rb1   hi 73728
  const size_t OFF_W1L  = 1925120;
  const size_t OFF_W2H  = 1998848;      // rb2   hi 73728
  const size_t OFF_W2L  = 2072576;
  const size_t OFF_WTH  = 2146304;      // tail  hi 204800
  const size_t OFF_WTL  = 2351104;
  const size_t OFF_WSH  = 2555904;      // sq    hi 409600
  const size_t OFF_WSL  = 2965504;
  const size_t OFF_P0H  = 3375104;
  const size_t OFF_P0L  = OFF_P0H + 2230272;   // 5,605,376
  const size_t OFF_P1H  = OFF_P0L + 2230272;   // 7,835,648
  const size_t OFF_P1L  = OFF_P1H + 2230272;   // 10,065,920 (end 12,296,192)
  const size_t OFF_SA   = 3375104;      // 4 MB: x1 -> T
  const size_t OFF_SB   = 7569408;      // 4 MB: hb -> dcf
  const size_t OFF_SC   = 11763712;     // 4 MB: xb

  float* ss0  = (float*)(ws + OFF_SS0);
  float* ss1  = (float*)(ws + OFF_SS1);
  float* inv0 = (float*)(ws + OFF_INV0);
  float* Sbuf = (float*)(ws + OFF_S);
  float* pval = (float*)(ws + OFF_PVAL);
  int*   pidx = (int*)(ws + OFF_PIDX);
  u16* whh = (u16*)(ws + OFF_WHH); u16* whl = (u16*)(ws + OFF_WHL);
  u16* w1h = (u16*)(ws + OFF_W1H); u16* w1l = (u16*)(ws + OFF_W1L);
  u16* w2h = (u16*)(ws + OFF_W2H); u16* w2l = (u16*)(ws + OFF_W2L);
  u16* wth = (u16*)(ws + OFF_WTH); u16* wtl = (u16*)(ws + OFF_WTL);
  u16* wsh = (u16*)(ws + OFF_WSH); u16* wsl = (u16*)(ws + OFF_WSL);
  u16* p0h = (u16*)(ws + OFF_P0H); u16* p0l = (u16*)(ws + OFF_P0L);
  u16* p1h = (u16*)(ws + OFF_P1H); u16* p1l = (u16*)(ws + OFF_P1L);
  float* x1  = (float*)(ws + OFF_SA);
  float* Tb  = (float*)(ws + OFF_SA);
  float* hb  = (float*)(ws + OFF_SB);
  float* dcf = (float*)(ws + OFF_SB);
  float* xb  = (float*)(ws + OFF_SC);

  dim3 b256(256);
  split_pad_kernel<<<dim3(1089, BATCH), b256, 0, stream>>>(c0, c1, p0h, p0l, p1h, p1l, ss0, ss1);
  wprep_all<<<dim3(1952), b256, 0, stream>>>(head_w, whh, whl,
      rb_w1 + 110592, w1h, w1l, rb_w2 + 110592, w2h, w2l,
      tail_w, wth, wtl, sq_w, wsh, wsl, ss0, inv0);

  corr_mfma<<<dim3(32, 8, BATCH), dim3(512), 0, stream>>>(p0h, p0l, p1h, p1l, inv0, pval, pidx);

  // conv stack (only residual block 3 affects output); all NHWC.
  // Stream-ordered: these overwrite the padded-split region, which is dead now.
  dim3 cgrid(128, BATCH);
  conv_mfma<5, 2><<<cgrid, b256, 0, stream>>>(c0, c1, whh, whl, head_b, x1, nullptr, nullptr, 0, 1);
  conv_mfma<3, 2><<<cgrid, b256, 0, stream>>>(x1, nullptr, w1h, w1l, rb_b1 + 192, hb, nullptr, nullptr, 1, 0);
  conv_mfma<3, 2><<<cgrid, b256, 0, stream>>>(hb, nullptr, w2h, w2l, rb_b2 + 192, xb, x1, nullptr, 0, 0);
  conv_mfma<5, 2><<<cgrid, b256, 0, stream>>>(xb, nullptr, wth, wtl, tail_b, dcf, x1, nullptr, 0, 0);

  // tgather (+fused reduce: argmax, inv1, S). x1 dead after conv4; Tb aliases it.
  tgather_kernel<<<dim3(64, BATCH), b256, 0, stream>>>(f0, pval, pidx, ss1, Sbuf, Tb);
  // conv5 with fused final: out = dcf + conv*S, written directly to output (NLC==NHWC)
  conv_mfma<5, 4><<<cgrid, b256, 0, stream>>>(dcf, Tb, wsh, wsl, sq_b, out, dcf, Sbuf, 0, 0);
}

// Round 8
// 491.092 us; speedup vs baseline: 1.0328x; 1.0287x over previous
//
#include <hip/hip_runtime.h>
#include <hip/hip_bf16.h>

// Texture_trans: patch-correlation texture transfer + residual conv stack.
// B=4, H=W=64, L=4096, C=64. ALL inputs/outputs fp32. Activations NHWC throughout.
// R20: corr phase body software-pipelined to break the read->MFMA convoy:
// reads A,B0,B1 upfront; then per j-cluster {prefetch B(j+2), 6 MFMA(j)} with
// sched_barrier(0) fences pinning the interleave. Window model: measured 3650
// cyc/window == LDS(1790) + MFMA(1862) serialized; interleave targets max() not
// sum(). All addresses/math/barriers identical to R19 (verified). Everything
// else byte-identical to R19. Workspace: 15,958,016 B.

#define BATCH 4

typedef unsigned short u16;
typedef unsigned int   u32;
typedef __attribute__((ext_vector_type(8))) short short8;
typedef __attribute__((ext_vector_type(4))) float f32x4;

__device__ __forceinline__ void bsplit2(float a, float b, u32& ho, u32& lo) {
  __hip_bfloat16 ha = __float2bfloat16(a), hb = __float2bfloat16(b);
  float ra = a - __bfloat162float(ha), rb = b - __bfloat162float(hb);
  __hip_bfloat16 la = __float2bfloat16(ra), lb = __float2bfloat16(rb);
  ho = (u32)*(u16*)&ha | ((u32)*(u16*)&hb << 16);
  lo = (u32)*(u16*)&la | ((u32)*(u16*)&lb << 16);
}

__device__ __forceinline__ void gload_lds16(const void* g, void* l) {
  __builtin_amdgcn_global_load_lds((const __attribute__((address_space(1))) void*)g,
                                   (__attribute__((address_space(3))) void*)l, 16, 0, 0);
}

// ---------------- K3: split fp32 -> bf16 hi + lo into ZERO-PADDED [B][66][66][64]
// + fused per-pixel channel sum-of-squares (lanes = channels, 64-lane shfl reduce).
__global__ __launch_bounds__(256) void split_pad_kernel(const float* __restrict__ c0,
    const float* __restrict__ c1, u16* __restrict__ p0h, u16* __restrict__ p0l,
    u16* __restrict__ p1h, u16* __restrict__ p1l,
    float* __restrict__ ss0, float* __restrict__ ss1)
{
  int b = blockIdx.y, t = threadIdx.x;
  int pix = blockIdx.x * 4 + (t >> 6);   // 0..4355 over 66x66
  int c = t & 63;
  int py = pix / 66, px = pix - py * 66;
  size_t d = ((size_t)b * 4356 + pix) * 64 + c;
  bool interior = (py >= 1 && py <= 64 && px >= 1 && px <= 64);
  float v0 = 0.f, v1 = 0.f;
  if (interior) {
    size_t s = (((size_t)b << 12) + ((py - 1) << 6) + (px - 1)) * 64 + c;
    v0 = c0[s]; v1 = c1[s];
  }
  __hip_bfloat16 h = __float2bfloat16(v0);
  float r = v0 - __bfloat162float(h);
  __hip_bfloat16 lo = __float2bfloat16(r);
  p0h[d] = *(u16*)&h; p0l[d] = *(u16*)&lo;
  h = __float2bfloat16(v1);
  r = v1 - __bfloat162float(h);
  lo = __float2bfloat16(r);
  p1h[d] = *(u16*)&h; p1l[d] = *(u16*)&lo;
  float s0 = v0 * v0, s1 = v1 * v1;
#pragma unroll
  for (int off = 32; off; off >>= 1) {
    s0 += __shfl_xor(s0, off);
    s1 += __shfl_xor(s1, off);
  }
  if (c == 0 && interior) {
    int sstid = (b << 12) + ((py - 1) << 6) + (px - 1);
    ss0[sstid] = s0;
    ss1[sstid] = s1;
  }
}

// ---------------- K3b: ALL weight sets + inv0 in one kernel.
__global__ __launch_bounds__(256) void wprep_all(
    const float* __restrict__ hw, u16* __restrict__ whh, u16* __restrict__ whl,
    const float* __restrict__ r1, u16* __restrict__ w1h, u16* __restrict__ w1l,
    const float* __restrict__ r2, u16* __restrict__ w2h, u16* __restrict__ w2l,
    const float* __restrict__ tw, u16* __restrict__ wth, u16* __restrict__ wtl,
    const float* __restrict__ sw, u16* __restrict__ wsh, u16* __restrict__ wsl,
    const float* __restrict__ ss0, float* __restrict__ inv0)
{
  int bid = blockIdx.x;
  if (bid >= 1888) {                     // inv0 tail: 64 blocks cover 4x4096
    int tid = (bid - 1888) * 256 + threadIdx.x;
    int b = tid >> 12, l = tid & 4095;
    int y = l >> 6, x = l & 63;
    const float* ssb = ss0 + (b << 12);
    float s = 0.f;
    for (int dy = -1; dy <= 1; ++dy) {
      int yy = y + dy; if ((unsigned)yy >= 64u) continue;
      for (int dx = -1; dx <= 1; ++dx) {
        int xx = x + dx; if ((unsigned)xx >= 64u) continue;
        s += ssb[(yy << 6) + xx];
      }
    }
    inv0[tid] = 1.f / fmaxf(sqrtf(s), 1e-12f);
    return;
  }
  const float* src; u16 *wh, *wl; int Cin, KK, n, i;
  if (bid < 400)       { src = hw; wh = whh; wl = whl; Cin = 64;  KK = 25; n = 102400; i = bid * 256; }
  else if (bid < 544)  { src = r1; wh = w1h; wl = w1l; Cin = 64;  KK = 9;  n = 36864;  i = (bid - 400) * 256; }
  else if (bid < 688)  { src = r2; wh = w2h; wl = w2l; Cin = 64;  KK = 9;  n = 36864;  i = (bid - 544) * 256; }
  else if (bid < 1088) { src = tw; wh = wth; wl = wtl; Cin = 64;  KK = 25; n = 102400; i = (bid - 688) * 256; }
  else                 { src = sw; wh = wsh; wl = wsl; Cin = 128; KK = 25; n = 204800; i = (bid - 1088) * 256; }
  i += threadIdx.x;
  if (i >= n) return;
  int per = Cin * KK;
  int cout = i / per;
  int rem = i - cout * per;
  int cin = rem / KK;
  int tap = rem - cin * KK;
  float x = src[i];
  __hip_bfloat16 h = __float2bfloat16(x);
  float r = x - __bfloat162float(h);
  __hip_bfloat16 lo = __float2bfloat16(r);
  int d = (tap * 64 + cout) * Cin + cin;
  wh[d] = *(u16*)&h;
  wl[d] = *(u16*)&lo;
}

// ---------------- K4: MFMA corr. R17/R19 8-wave structure + pipelined phase body.
__global__ __launch_bounds__(512) void corr_mfma(const u16* __restrict__ p0h,
    const u16* __restrict__ p0l, const u16* __restrict__ p1h, const u16* __restrict__ p1l,
    const float* __restrict__ inv0, float* __restrict__ pval, int* __restrict__ pidx)
{
  __shared__ __align__(16) u16 smem[32768];   // 64 KB: 2 buf x (4 matrices x 4096)
  int mt = blockIdx.x, lt = blockIdx.y, b = blockIdx.z;
  int t = threadIdx.x;
  int lane = t & 63, w = t >> 6;              // w in 0..7
  int wa = w >> 1, wm = w & 1;                // A-quarter / B-half (compute)
  int mat = w >> 1, half = w & 1;             // staging matrix / half
  int cc = lane & 15, q = lane >> 4;
  const size_t boff = (size_t)b * 278784;     // 66*66*64
  const u16* msrc = (mat == 0) ? p0h : (mat == 1) ? p0l : (mat == 2) ? p1h : p1l;
  msrc += boff;
  const float* inv0b = inv0 + (b << 12);
  int isB = mat >> 1;

  int srow0 = lane >> 2;                      // row within 16-row chunk
  int cs_g  = (lane & 3) ^ ((lane >> 3) & 3); // source chunk for this lane's slot
  int sw    = (cc >> 1) & 3;                  // read-side swizzle key

  const u16* gb[4];
#pragma unroll
  for (int ii = 0; ii < 4; ++ii) {
    int k = ((half * 4 + ii) << 4) + srow0;   // pixel offset within 128-row tile
    gb[ii] = msrc + ((((k >> 6) * 66) + (k & 63)) << 6) + (cs_g << 3);
  }

  auto stage = [&](int ssub, int sph, u16* dstbase) {
    int r = sph >> 1, hh = sph & 1;
    int ki = r / 3, kj = r - ki * 3;
    int pbr = isB ? (mt << 1) : ((lt << 3) + (ssub << 1));   // pb>>6 (rows)
    int uoff = (((pbr + ki) * 66 + kj) << 6) + (hh << 5);    // wave-uniform
#pragma unroll
    for (int ii = 0; ii < 4; ++ii)
      gload_lds16(gb[ii] + uoff, dstbase + ((half * 4 + ii) << 9));
  };

  float bval[4] = {-1e30f, -1e30f, -1e30f, -1e30f};
  int   bidx[4] = {0, 0, 0, 0};

  stage(0, 0, smem + (mat << 12));            // prologue into buffer 0

  for (int sub = 0; sub < 4; ++sub) {
    int row0 = (lt << 9) + (sub << 7);
    f32x4 acc[2][4];
#pragma unroll
    for (int i = 0; i < 2; ++i)
#pragma unroll
      for (int j = 0; j < 4; ++j) acc[i][j] = (f32x4){0.f, 0.f, 0.f, 0.f};

    for (int ph = 0; ph < 18; ++ph) {
      int g = sub * 18 + ph;
      int nxt = g + 1;
      if (nxt < 72) {
        int np = ph + 1, ns = sub;
        if (np == 18) { np = 0; ++ns; }
        stage(ns, np, smem + ((nxt & 1) << 14) + (mat << 12));
        asm volatile("s_waitcnt vmcnt(4)" ::: "memory");   // phase g landed; g+1 in flight
      } else {
        asm volatile("s_waitcnt vmcnt(0)" ::: "memory");
      }
      __builtin_amdgcn_s_barrier();
      __builtin_amdgcn_sched_barrier(0);
      const u16* bb = smem + ((g & 1) << 14);
      short8 afh[2], afl[2], bfh[4], bfl[4];
      // front reads: A (4) + B0,B1 (4)
#pragma unroll
      for (int i = 0; i < 2; ++i) {
        int ra = (((wa << 5) + (i << 4) + cc) << 5) + ((q ^ sw) << 3);
        afh[i] = *(const short8*)(&bb[ra]);
        afl[i] = *(const short8*)(&bb[4096 + ra]);
      }
#pragma unroll
      for (int j = 0; j < 2; ++j) {
        int rb = (((wm << 6) + (j << 4) + cc) << 5) + ((q ^ sw) << 3);
        bfh[j] = *(const short8*)(&bb[8192 + rb]);
        bfl[j] = *(const short8*)(&bb[12288 + rb]);
      }
      __builtin_amdgcn_s_setprio(1);
      // j-clusters: prefetch B(j+2) reads, then 6 MFMA for j; fences pin order
#pragma unroll
      for (int j = 0; j < 4; ++j) {
        if (j < 2) {
          int rb = (((wm << 6) + ((j + 2) << 4) + cc) << 5) + ((q ^ sw) << 3);
          bfh[j + 2] = *(const short8*)(&bb[8192 + rb]);
          bfl[j + 2] = *(const short8*)(&bb[12288 + rb]);
        }
        __builtin_amdgcn_sched_barrier(0);
        acc[0][j] = __builtin_amdgcn_mfma_f32_16x16x32_bf16(afh[0], bfl[j], acc[0][j], 0, 0, 0);
        acc[0][j] = __builtin_amdgcn_mfma_f32_16x16x32_bf16(afl[0], bfh[j], acc[0][j], 0, 0, 0);
        acc[0][j] = __builtin_amdgcn_mfma_f32_16x16x32_bf16(afh[0], bfh[j], acc[0][j], 0, 0, 0);
        acc[1][j] = __builtin_amdgcn_mfma_f32_16x16x32_bf16(afh[1], bfl[j], acc[1][j], 0, 0, 0);
        acc[1][j] = __builtin_amdgcn_mfma_f32_16x16x32_bf16(afl[1], bfh[j], acc[1][j], 0, 0, 0);
        acc[1][j] = __builtin_amdgcn_mfma_f32_16x16x32_bf16(afh[1], bfh[j], acc[1][j], 0, 0, 0);
        __builtin_amdgcn_sched_barrier(0);
      }
      __builtin_amdgcn_s_setprio(0);
      __builtin_amdgcn_sched_barrier(0);
      __builtin_amdgcn_s_barrier();          // readers done before buf re-staged
    }
#pragma unroll
    for (int i = 0; i < 2; ++i) {
#pragma unroll
      for (int rg = 0; rg < 4; ++rg) {
        int l = row0 + (wa << 5) + (i << 4) + (q << 2) + rg;
        float sc = inv0b[l];
#pragma unroll
        for (int j = 0; j < 4; ++j) {
          float v = acc[i][j][rg] * sc;
          if (v > bval[j]) { bval[j] = v; bidx[j] = l; }
        }
      }
    }
  }

  __syncthreads();                            // tiles dead; alias reduce buffers
  float* lval = (float*)smem;                 // 128 cols x 16 slots = 8 KB
  int*   lidx = (int*)((char*)smem + 8192);   // 8 KB
  int slot = (wa << 2) + q;
#pragma unroll
  for (int j = 0; j < 4; ++j) {
    int col = (wm << 6) + (j << 4) + cc;
    lval[col * 16 + slot] = bval[j];
    lidx[col * 16 + slot] = bidx[j];
  }
  __syncthreads();
  if (t < 128) {
    float bv = -1e30f; int bi = 0x7FFFFFFF;
    for (int s = 0; s < 16; ++s) {
      float v = lval[t * 16 + s]; int id = lidx[t * 16 + s];
      if (v > bv || (v == bv && id < bi)) { bv = v; bi = id; }
    }
    size_t o = (size_t)(((b << 3) + lt) << 12) + (mt << 7) + t;
    pval[o] = bv; pidx[o] = bi;
  }
}

// ---------------- K6: T = fold3(gather(f0_unfold, arg))/9 -> NHWC fp32.
// Fused reduce: argmax from pval/pidx for its 3 rows; inv1 + S for its own row.
__global__ __launch_bounds__(256) void tgather_kernel(const float* __restrict__ f0,
    const float* __restrict__ pval, const int* __restrict__ pidx,
    const float* __restrict__ ss1, float* __restrict__ S, float* __restrict__ T)
{
  __shared__ int a3[192];
  int y = blockIdx.x, b = blockIdx.y, t = threadIdx.x;
  if (t < 192) {
    int r = t >> 6, xx = t & 63;
    int yy = y + r - 1;
    bool ok = (yy >= 0 && yy < 64);
    float bv = -1e30f; int bi = 0x7FFFFFFF;
    if (ok) {
      int m = (yy << 6) + xx;
      for (int ltv = 0; ltv < 8; ++ltv) {
        size_t o = (size_t)(((b << 3) + ltv) << 12) + m;
        float v = pval[o]; int id = pidx[o];
        if (v > bv || (v == bv && id < bi)) { bv = v; bi = id; }
      }
      if (r == 1) {  // own row: compute inv1, write S
        const float* ssb = ss1 + (b << 12);
        float s = 0.f;
        for (int dy = -1; dy <= 1; ++dy) {
          int y2 = yy + dy; if ((unsigned)y2 >= 64u) continue;
          for (int dx = -1; dx <= 1; ++dx) {
            int x2 = xx + dx; if ((unsigned)x2 >= 64u) continue;
            s += ssb[(y2 << 6) + x2];
          }
        }
        S[(b << 12) + m] = bv / fmaxf(sqrtf(s), 1e-12f);
      }
    }
    a3[t] = (ok && (unsigned)bi < 4096u) ? bi : 0;
  }
  __syncthreads();
  int c = t & 63, pg = t >> 6;
  for (int it = 0; it < 16; ++it) {
    int px = pg + (it << 2);
    float sum = 0.f;
#pragma unroll
    for (int ki = 0; ki < 3; ++ki) {
      int yn = y + 1 - ki;
      if (yn < 0 || yn >= 64) continue;
#pragma unroll
      for (int kj = 0; kj < 3; ++kj) {
        int xn = px + 1 - kj;
        if (xn < 0 || xn >= 64) continue;
        int p = a3[((2 - ki) << 6) + xn];
        int sy = (p >> 6) + ki - 1, sx = (p & 63) + kj - 1;
        if (sy >= 0 && sy < 64 && sx >= 0 && sx < 64)
          sum += f0[((((size_t)b << 12) + (sy << 6) + sx) << 6) + c];
      }
    }
    T[((((size_t)b << 12) + (y << 6) + px)) * 64 + c] = sum * (1.f / 9.f);
  }
}

// ---------------- K7: implicit-GEMM MFMA conv (unchanged R16-R19).
template<int KS, int CINCH>
__global__ __launch_bounds__(256) void conv_mfma(const float* __restrict__ in0,
    const float* __restrict__ in1, const u16* __restrict__ whp, const u16* __restrict__ wlp,
    const float* __restrict__ bias, float* __restrict__ outp,
    const float* __restrict__ res, const float* __restrict__ smul, int dorelu, int dm)
{
  constexpr int P = KS / 2;
  constexpr int CIN = CINCH * 32;
  constexpr int NKH = CINCH / 2;              // # of 64-cin units
  constexpr int NIT = KS * KS * NKH;
  constexpr int AST = 72;                     // row stride in u16 (144 B, 16B-aligned)
  __shared__ __align__(16) u16 Ah[2][32 * AST], Al[2][32 * AST];
  __shared__ __align__(16) u16 Bh[2][64 * AST], Bl[2][64 * AST];
  int tile = blockIdx.x, b = blockIdx.y;      // y = tile>>1, px half = tile&1
  int t = threadIdx.x;
  int lane = t & 63, w = t >> 6;
  int wpx = w >> 1, wm = w & 1;
  int cc = lane & 15, q = lane >> 4;
  int ty = tile >> 1, txb = (tile & 1) << 5;
  const size_t abase = (size_t)b << 12;
  f32x4 acc[2];
  acc[0] = (f32x4){0.f, 0.f, 0.f, 0.f};
  acc[1] = (f32x4){0.f, 0.f, 0.f, 0.f};

  uint4 rg[8];                                // staging regs
  int arow = t >> 2, acs = t & 3;             // A mapping (t<128): 16-ch quarter
  int tb = t - 128;                           // B mapping (t>=128)
  int brow = tb >> 1, bhalf = tb & 1;         // 64 rows x 2 halves of 32 ch

  auto issue_loads = [&](int itn) {
    int tapn = (NKH == 1) ? itn : (itn >> 1);
    int kh   = (NKH == 1) ? 0 : (itn & 1);
    int ki = tapn / KS, kj = tapn - ki * KS;
    if (t < 128) {
#pragma unroll
      for (int k = 0; k < 8; ++k) rg[k] = make_uint4(0u, 0u, 0u, 0u);
      int iy = ty + ki - P;
      int ix = txb + arow + kj - P;
      if ((unsigned)iy < 64u && (unsigned)ix < 64u) {
        size_t base = (abase + (iy << 6) + ix) << 6;
        int cg = kh * 64 + acs * 16;
        if (dm) {
#pragma unroll
          for (int k = 0; k < 4; ++k) {
            rg[k]     = *(const uint4*)(in0 + base + cg + 4 * k);
            rg[4 + k] = *(const uint4*)(in1 + base + cg + 4 * k);
          }
        } else {
          const float* sp = (CINCH == 4 && kh == 1) ? (in1 + base + (cg - 64))
                                                    : (in0 + base + cg);
#pragma unroll
          for (int k = 0; k < 4; ++k) rg[k] = *(const uint4*)(sp + 4 * k);
        }
      }
    } else {
      size_t so = (size_t)(tapn * 64 + brow) * CIN + kh * 64 + bhalf * 32;
#pragma unroll
      for (int k = 0; k < 4; ++k) {
        rg[k]     = *(const uint4*)&whp[so + 8 * k];
        rg[4 + k] = *(const uint4*)&wlp[so + 8 * k];
      }
    }
  };

  auto write_lds = [&](int cur) {
    if (t < 128) {
      float v[16];
      if (dm) {
#pragma unroll
        for (int k = 0; k < 4; ++k)
#pragma unroll
          for (int e = 0; e < 4; ++e)
            v[k * 4 + e] = __uint_as_float((&rg[4 + k].x)[e]) - __uint_as_float((&rg[k].x)[e]);
      } else {
#pragma unroll
        for (int k = 0; k < 4; ++k)
#pragma unroll
          for (int e = 0; e < 4; ++e)
            v[k * 4 + e] = __uint_as_float((&rg[k].x)[e]);
      }
      uint4 uh0, ul0, uh1, ul1;
      bsplit2(v[0], v[1], uh0.x, ul0.x);
      bsplit2(v[2], v[3], uh0.y, ul0.y);
      bsplit2(v[4], v[5], uh0.z, ul0.z);
      bsplit2(v[6], v[7], uh0.w, ul0.w);
      bsplit2(v[8], v[9], uh1.x, ul1.x);
      bsplit2(v[10], v[11], uh1.y, ul1.y);
      bsplit2(v[12], v[13], uh1.z, ul1.z);
      bsplit2(v[14], v[15], uh1.w, ul1.w);
      int o = arow * AST + acs * 16;
      *(uint4*)&Ah[cur][o]     = uh0;
      *(uint4*)&Ah[cur][o + 8] = uh1;
      *(uint4*)&Al[cur][o]     = ul0;
      *(uint4*)&Al[cur][o + 8] = ul1;
    } else {
      int o = brow * AST + bhalf * 32;
#pragma unroll
      for (int k = 0; k < 4; ++k) {
        *(uint4*)&Bh[cur][o + 8 * k] = rg[k];
        *(uint4*)&Bl[cur][o + 8 * k] = rg[4 + k];
      }
    }
  };

  issue_loads(0);
  for (int it = 0; it < NIT; ++it) {
    int cur = it & 1;
    write_lds(cur);                            // consumes rg (vmcnt waits auto)
    if (it + 1 < NIT) issue_loads(it + 1);     // in flight across the barrier
    asm volatile("s_waitcnt lgkmcnt(0)" ::: "memory");
    __builtin_amdgcn_s_barrier();
    __builtin_amdgcn_sched_barrier(0);
    short8 afh[2], afl[2], bfh[2][2], bfl[2][2];
#pragma unroll
    for (int ks = 0; ks < 2; ++ks) {
      int ra = ((wpx << 4) + cc) * AST + ks * 32 + (q << 3);
      afh[ks] = *(const short8*)&Ah[cur][ra];
      afl[ks] = *(const short8*)&Al[cur][ra];
#pragma unroll
      for (int j = 0; j < 2; ++j) {
        int rb = ((wm << 5) + (j << 4) + cc) * AST + ks * 32 + (q << 3);
        bfh[j][ks] = *(const short8*)&Bh[cur][rb];
        bfl[j][ks] = *(const short8*)&Bl[cur][rb];
      }
    }
#pragma unroll
    for (int ks = 0; ks < 2; ++ks) {
      acc[0] = __builtin_amdgcn_mfma_f32_16x16x32_bf16(afh[ks], bfl[0][ks], acc[0], 0, 0, 0);
      acc[1] = __builtin_amdgcn_mfma_f32_16x16x32_bf16(afh[ks], bfl[1][ks], acc[1], 0, 0, 0);
      acc[0] = __builtin_amdgcn_mfma_f32_16x16x32_bf16(afl[ks], bfh[0][ks], acc[0], 0, 0, 0);
      acc[1] = __builtin_amdgcn_mfma_f32_16x16x32_bf16(afl[ks], bfh[1][ks], acc[1], 0, 0, 0);
      acc[0] = __builtin_amdgcn_mfma_f32_16x16x32_bf16(afh[ks], bfh[0][ks], acc[0], 0, 0, 0);
      acc[1] = __builtin_amdgcn_mfma_f32_16x16x32_bf16(afh[ks], bfh[1][ks], acc[1], 0, 0, 0);
    }
  }
#pragma unroll
  for (int rgi = 0; rgi < 4; ++rgi) {
    int p = (ty << 6) + txb + (wpx << 4) + (q << 2) + rgi;
#pragma unroll
    for (int j = 0; j < 2; ++j) {
      int cout = (wm << 5) + (j << 4) + cc;
      float v = acc[j][rgi] + bias[cout];
      if (dorelu) v = fmaxf(v, 0.f);
      size_t oi = ((abase + p) << 6) + cout;
      if (smul) v = res[oi] + v * smul[abase + p];
      else if (res) v += res[oi];
      outp[oi] = v;
    }
  }
}

extern "C" void kernel_launch(void* const* d_in, const int* in_sizes, int n_in,
                              void* d_out, int out_size, void* d_ws, size_t ws_size,
                              hipStream_t stream)
{
  (void)in_sizes; (void)n_in; (void)out_size; (void)ws_size;
  const float* c0     = (const float*)d_in[0];
  const float* f0     = (const float*)d_in[1];
  const float* c1     = (const float*)d_in[2];
  const float* head_w = (const float*)d_in[3];
  const float* head_b = (const float*)d_in[4];
  const float* rb_w1  = (const float*)d_in[5];
  const float* rb_b1  = (const float*)d_in[6];
  const float* rb_w2  = (const float*)d_in[7];
  const float* rb_b2  = (const float*)d_in[8];
  const float* tail_w = (const float*)d_in[9];
  const float* tail_b = (const float*)d_in[10];
  const float* sq_w   = (const float*)d_in[11];
  const float* sq_b   = (const float*)d_in[12];
  float* out = (float*)d_out;
  char* ws = (char*)d_ws;

  // ---- layout: 15,958,016 B total (unchanged) ----
  const size_t OFF_SS0  = 0;
  const size_t OFF_SS1  = 65536;
  const size_t OFF_INV0 = 131072;
  const size_t OFF_S    = 262144;
  const size_t OFF_PVAL = 393216;       // 512 KB
  const size_t OFF_PIDX = 917504;       // 512 KB
  const size_t OFF_WHH  = 1441792;      // head  hi 204800
  const size_t OFF_WHL  = 1646592;      // head  lo 204800
  const size_t OFF_W1H  = 1851392;      // rb1   hi 73728
  const size_t OFF_W1L  = 1925120;
  const size_t OFF_W2H  = 1998848;      // rb2   hi 73728
  const size_t OFF_W2L  = 2072576;
  const size_t OFF_WTH  = 2146304;      // tail  hi 204800
  const size_t OFF_WTL  = 2351104;
  const size_t OFF_WSH  = 2555904;      // sq    hi 409600
  const size_t OFF_WSL  = 2965504;
  const size_t OFF_P0H  = 3375104;
  const size_t OFF_P0L  = OFF_P0H + 2230272;   // 5,605,376
  const size_t OFF_P1H  = OFF_P0L + 2230272;   // 7,835,648
  const size_t OFF_P1L  = OFF_P1H + 2230272;   // 10,065,920 (end 12,296,192)
  const size_t OFF_SA   = 3375104;      // 4 MB: x1 -> T
  const size_t OFF_SB   = 7569408;      // 4 MB: hb -> dcf
  const size_t OFF_SC   = 11763712;     // 4 MB: xb

  float* ss0  = (float*)(ws + OFF_SS0);
  float* ss1  = (float*)(ws + OFF_SS1);
  float* inv0 = (float*)(ws + OFF_INV0);
  float* Sbuf = (float*)(ws + OFF_S);
  float* pval = (float*)(ws + OFF_PVAL);
  int*   pidx = (int*)(ws + OFF_PIDX);
  u16* whh = (u16*)(ws + OFF_WHH); u16* whl = (u16*)(ws + OFF_WHL);
  u16* w1h = (u16*)(ws + OFF_W1H); u16* w1l = (u16*)(ws + OFF_W1L);
  u16* w2h = (u16*)(ws + OFF_W2H); u16* w2l = (u16*)(ws + OFF_W2L);
  u16* wth = (u16*)(ws + OFF_WTH); u16* wtl = (u16*)(ws + OFF_WTL);
  u16* wsh = (u16*)(ws + OFF_WSH); u16* wsl = (u16*)(ws + OFF_WSL);
  u16* p0h = (u16*)(ws + OFF_P0H); u16* p0l = (u16*)(ws + OFF_P0L);
  u16* p1h = (u16*)(ws + OFF_P1H); u16* p1l = (u16*)(ws + OFF_P1L);
  float* x1  = (float*)(ws + OFF_SA);
  float* Tb  = (float*)(ws + OFF_SA);
  float* hb  = (float*)(ws + OFF_SB);
  float* dcf = (float*)(ws + OFF_SB);
  float* xb  = (float*)(ws + OFF_SC);

  dim3 b256(256);
  split_pad_kernel<<<dim3(1089, BATCH), b256, 0, stream>>>(c0, c1, p0h, p0l, p1h, p1l, ss0, ss1);
  wprep_all<<<dim3(1952), b256, 0, stream>>>(head_w, whh, whl,
      rb_w1 + 110592, w1h, w1l, rb_w2 + 110592, w2h, w2l,
      tail_w, wth, wtl, sq_w, wsh, wsl, ss0, inv0);

  corr_mfma<<<dim3(32, 8, BATCH), dim3(512), 0, stream>>>(p0h, p0l, p1h, p1l, inv0, pval, pidx);

  // conv stack (only residual block 3 affects output); all NHWC.
  // Stream-ordered: these overwrite the padded-split region, which is dead now.
  dim3 cgrid(128, BATCH);
  conv_mfma<5, 2><<<cgrid, b256, 0, stream>>>(c0, c1, whh, whl, head_b, x1, nullptr, nullptr, 0, 1);
  conv_mfma<3, 2><<<cgrid, b256, 0, stream>>>(x1, nullptr, w1h, w1l, rb_b1 + 192, hb, nullptr, nullptr, 1, 0);
  conv_mfma<3, 2><<<cgrid, b256, 0, stream>>>(hb, nullptr, w2h, w2l, rb_b2 + 192, xb, x1, nullptr, 0, 0);
  conv_mfma<5, 2><<<cgrid, b256, 0, stream>>>(xb, nullptr, wth, wtl, tail_b, dcf, x1, nullptr, 0, 0);

  // tgather (+fused reduce: argmax, inv1, S). x1 dead after conv4; Tb aliases it.
  tgather_kernel<<<dim3(64, BATCH), b256, 0, stream>>>(f0, pval, pidx, ss1, Sbuf, Tb);
  // conv5 with fused final: out = dcf + conv*S, written directly to output (NLC==NHWC)
  conv_mfma<5, 4><<<cgrid, b256, 0, stream>>>(dcf, Tb, wsh, wsl, sq_b, out, dcf, Sbuf, 0, 0);
}